// Round 7
// baseline (637.911 us; speedup 1.0000x reference)
//
#include <hip/hip_runtime.h>

// ---------- types / helpers ----------
typedef __attribute__((ext_vector_type(8))) short bf16x8;   // MFMA A/B frag (4 VGPRs)
typedef __attribute__((ext_vector_type(4))) float f32x4;    // MFMA C/D frag
typedef __attribute__((ext_vector_type(4))) unsigned short us4_t;   // 8B bf16 store
typedef __attribute__((ext_vector_type(4))) unsigned int u32x4;    // 16B LDS write

__device__ __forceinline__ unsigned short f2bf(float f) {   // RNE fp32->bf16
  unsigned u = __builtin_bit_cast(unsigned, f);
  u += 0x7fffu + ((u >> 16) & 1u);
  return (unsigned short)(u >> 16);
}
__device__ __forceinline__ float bf2f(unsigned short h) {
  unsigned u = ((unsigned)h) << 16;
  return __builtin_bit_cast(float, u);
}
// async global->LDS DMA, 16B/lane. LDS dst is wave-uniform base + lane*16 (m97/m104).
__device__ __forceinline__ void async16(void* lds, const void* g) {
  __builtin_amdgcn_global_load_lds(
      (const __attribute__((address_space(1))) unsigned int*)g,
      (__attribute__((address_space(3))) unsigned int*)lds, 16, 0, 0);
}

#define LOG2E 1.44269504088896340736f

// ---------- K_pre0: x fp32 -> bf16 (flat) ----------
__global__ __launch_bounds__(256) void xcvt_kernel(const float* __restrict__ x,
                                                   unsigned short* __restrict__ xb) {
  size_t base = ((size_t)blockIdx.x * 256 + threadIdx.x) * 16;
  #pragma unroll
  for (int i = 0; i < 4; i++) {
    float4 v = *(const float4*)(x + base + i * 4);
    us4_t p;
    p[0] = f2bf(v.x); p[1] = f2bf(v.y); p[2] = f2bf(v.z); p[3] = f2bf(v.w);
    *(us4_t*)(xb + base + i * 4) = p;
  }
}

// ---------- K_pre1: w [256][N] fp32 -> wT [N][256] bf16 (transpose+convert, once) ----------
__global__ __launch_bounds__(256) void wtcvt_kernel(const float* __restrict__ w,
                                                    unsigned short* __restrict__ wT, int N) {
  int flat = (blockIdx.x * 256 + threadIdx.x) * 4;   // over 256*N elems
  int k = flat / N, n = flat - k * N;                // 4 consecutive n, same k
  float4 v = *(const float4*)(w + flat);
  wT[(size_t)(n + 0) * 256 + k] = f2bf(v.x);
  wT[(size_t)(n + 1) * 256 + k] = f2bf(v.y);
  wT[(size_t)(n + 2) * 256 + k] = f2bf(v.z);
  wT[(size_t)(n + 3) * 256 + k] = f2bf(v.w);
}

// ---------- K0: rank-factored neural position bias -> bq/bk [H][256][32] bf16 ----------
// 64 blocks x 4 rows; hf in LDS (no scratch), coalesced mlp2_w float4 reads.
// bq carries bias_scale * log2(e) so attention softmax can run in exp2 domain.
__global__ __launch_bounds__(256) void bias_kernel(
    const float* __restrict__ mlp1_w, const float* __restrict__ mlp1_b,
    const float* __restrict__ mlp2_w, const float* __restrict__ bias_scale,
    unsigned short* __restrict__ bq_ws, unsigned short* __restrict__ bk_ws) {
  __shared__ float hf_s[4][128];     // 2 KB
  const int tid = threadIdx.x;
  const int nb = blockIdx.x * 4;     // 64 blocks cover n = 0..255
  const float inv_denom = 0.36067376022224085f;  // 1/log(16)

  // phase 1: 512 hf values per block, 2 per thread (2 erff/thread)
  #pragma unroll
  for (int i = 0; i < 2; i++) {
    int idx = tid + i * 256;                  // 0..511
    int nl = idx >> 7, j = idx & 127;
    int n = nb + nl;
    float c0 = log1pf((float)(n >> 4)) * inv_denom;
    float c1 = log1pf((float)(n & 15)) * inv_denom;
    float t = fmaf(c0, mlp1_w[j], fmaf(c1, mlp1_w[128 + j], mlp1_b[j]));
    hf_s[nl][j] = 0.5f * t * (1.0f + erff(t * 0.70710678118654752f));  // exact gelu
  }
  __syncthreads();

  // phase 2: thread -> (n = nb + tid>>6, cols c0i..c0i+7). hf via LDS broadcast,
  // mlp2_w row j read coalesced (wave covers the 512-float row contiguously).
  const int nl = tid >> 6, n = nb + nl;
  const int c0i = (tid & 63) * 8;
  float acc[8];
  #pragma unroll
  for (int i = 0; i < 8; i++) acc[i] = 0.f;
  for (int j = 0; j < 128; j++) {
    float hv = hf_s[nl][j];
    const float4 w0 = *(const float4*)(mlp2_w + j * 512 + c0i);
    const float4 w1 = *(const float4*)(mlp2_w + j * 512 + c0i + 4);
    acc[0] = fmaf(hv, w0.x, acc[0]); acc[1] = fmaf(hv, w0.y, acc[1]);
    acc[2] = fmaf(hv, w0.z, acc[2]); acc[3] = fmaf(hv, w0.w, acc[3]);
    acc[4] = fmaf(hv, w1.x, acc[4]); acc[5] = fmaf(hv, w1.y, acc[5]);
    acc[6] = fmaf(hv, w1.z, acc[6]); acc[7] = fmaf(hv, w1.w, acc[7]);
  }
  // c = h*64 + qk*32 + r  (8 consecutive r within one (h,qk) block)
  const int h = c0i >> 6, qk = (c0i >> 5) & 1, rb = c0i & 31;
  const float fac = qk ? 1.0f : bias_scale[0] * LOG2E;
  unsigned short* dst = (qk ? bk_ws : bq_ws) + ((size_t)(h * 256 + n)) * 32 + rb;
  us4_t p0, p1;
  #pragma unroll
  for (int i = 0; i < 4; i++) p0[i] = f2bf(fac / (1.f + expf(-acc[i])));
  #pragma unroll
  for (int i = 0; i < 4; i++) p1[i] = f2bf(fac / (1.f + expf(-acc[4 + i])));
  *(us4_t*)dst = p0;
  *(us4_t*)(dst + 4) = p1;
}

// ---------- K1: qkv GEMM (m97 structure). A=xb [M][256], B=wT [768][256], both bf16 k-contig.
// 128x128 tile, BK=64, 256 threads; DMA staging, unpadded stride-64 LDS.
// R7: v columns stored KEY-PERMUTED phi(n)=(n&15)*16+(n>>4) so attn can write P
// as contiguous 32B runs (packed cvt_pk + ds_write_b128). phi is an involution;
// attention output is invariant under a consistent key permutation of K/bk/V.
__global__ __launch_bounds__(256) void qkv_kernel(
    const unsigned short* __restrict__ xb, const unsigned short* __restrict__ wT,
    const float* __restrict__ wb, const float* __restrict__ logit_scale,
    unsigned short* __restrict__ q_ws, unsigned short* __restrict__ k_ws,
    unsigned short* __restrict__ v_ws) {
  __shared__ unsigned short As[128 * 64];
  __shared__ unsigned short Bs[128 * 64];
  const int tid = threadIdx.x;
  const int n0 = blockIdx.x * 128, r0 = blockIdx.y * 128;
  const int lane = tid & 63, wv = tid >> 6, quad = lane >> 4, l15 = lane & 15;
  const int wm = (wv & 1) * 64, wn = (wv >> 1) * 64;

  f32x4 acc[4][4];
  #pragma unroll
  for (int i = 0; i < 4; i++)
    #pragma unroll
    for (int j = 0; j < 4; j++) acc[i][j] = (f32x4){0.f, 0.f, 0.f, 0.f};

  for (int kk = 0; kk < 256; kk += 64) {
    __syncthreads();
    #pragma unroll
    for (int i = 0; i < 4; i++) {            // flat = tid*8 + i*2048: lane-contig 16B
      int flat = tid * 8 + i * 2048;
      int row = flat >> 6, kc = flat & 63;
      async16(&As[flat], xb + (size_t)(r0 + row) * 256 + kk + kc);
      async16(&Bs[flat], wT + (size_t)(n0 + row) * 256 + kk + kc);
    }
    __syncthreads();                          // barrier drains vmcnt (m97)
    bf16x8 a[4][2], b[4][2];
    #pragma unroll
    for (int rt = 0; rt < 4; rt++) {
      a[rt][0] = *(const bf16x8*)(&As[(wm + rt * 16 + l15) * 64 + quad * 8]);
      a[rt][1] = *(const bf16x8*)(&As[(wm + rt * 16 + l15) * 64 + 32 + quad * 8]);
    }
    #pragma unroll
    for (int ct = 0; ct < 4; ct++) {
      b[ct][0] = *(const bf16x8*)(&Bs[(wn + ct * 16 + l15) * 64 + quad * 8]);
      b[ct][1] = *(const bf16x8*)(&Bs[(wn + ct * 16 + l15) * 64 + 32 + quad * 8]);
    }
    #pragma unroll
    for (int rt = 0; rt < 4; rt++)
      #pragma unroll
      for (int ct = 0; ct < 4; ct++) {
        acc[rt][ct] = __builtin_amdgcn_mfma_f32_16x16x32_bf16(a[rt][0], b[ct][0], acc[rt][ct], 0, 0, 0);
        acc[rt][ct] = __builtin_amdgcn_mfma_f32_16x16x32_bf16(a[rt][1], b[ct][1], acc[rt][ct], 0, 0, 0);
      }
  }
  // epilogue (verified R1): C/D layout col=lane&15, row=quad*4+reg
  #pragma unroll
  for (int rt = 0; rt < 4; rt++) {
    const int rowb = r0 + wm + rt * 16 + quad * 4;
    const int bb = rowb >> 8, n = rowb & 255;
    #pragma unroll
    for (int ct = 0; ct < 4; ct++) {
      const int gc = n0 + wn + ct * 16 + l15;
      const int s = gc >> 8, rem = gc & 255, h = rem >> 5, d = rem & 31;
      const float bc = wb[gc];
      if (s == 2) {  // v transposed [B,H,32,phi(N)] — key-permuted columns
        unsigned short* vrow = v_ws + ((size_t)(bb * 8 + h) * 32 + d) * 256;
        #pragma unroll
        for (int r = 0; r < 4; r++) {
          int nn = n + r;
          vrow[((nn & 15) << 4) | (nn >> 4)] = f2bf(acc[rt][ct][r] + bc);
        }
      } else {
        // fold log2e into q so attention softmax runs in exp2 domain
        const float sc = (s == 0) ? logit_scale[h] * LOG2E : 1.0f;
        unsigned short* dst = (s == 0) ? q_ws : k_ws;
        #pragma unroll
        for (int r = 0; r < 4; r++)
          dst[((size_t)(bb * 8 + h) * 256 + (n + r)) * 32 + d] = f2bf((acc[rt][ct][r] + bc) * sc);
      }
    }
  }
}

// ---------- K2: attention per (b,h). LDS = exactly 80 KB -> 2 blocks/CU.
// R7: P stored in phi-permuted key space (v_ws pre-permuted by qkv): lane's 16
// softmax values per row are CONTIGUOUS -> 8x v_cvt_pk_bf16_f32 + 2x ds_write_b128
// per row (was 64 scalar f2bf + 64 ds_write_b16 per rt). PV/vT/v_mean unchanged.
__global__ __launch_bounds__(256, 2) void attn_kernel(
    const unsigned short* __restrict__ q_ws, const unsigned short* __restrict__ k_ws,
    const unsigned short* __restrict__ v_ws, const unsigned short* __restrict__ bq_ws,
    const unsigned short* __restrict__ bk_ws, const float* __restrict__ val_res_scale,
    unsigned short* __restrict__ attn_ws) {
  __shared__ unsigned short kk_s[256 * 32];   // [key][d]   swizzled  16 KB
  __shared__ unsigned short bk_s[256 * 32];   // [key][r]   swizzled  16 KB
  __shared__ unsigned short vT[32 * 256];     // [d][pos]   swizzled  16 KB (pos = phi(key))
  __shared__ unsigned short Pb[4][16 * 256];  // per-wave P, XOR-swizzled chunks  32 KB

  const int tid = threadIdx.x;
  const int bh = blockIdx.x, b = bh >> 3, h = bh & 7;
  const size_t base = (size_t)bh * (256 * 32);
  const int lane = tid & 63, wv = tid >> 6, quad = lane >> 4, l15 = lane & 15;

  // staging: linear LDS dest + pre-swizzled global source (rule 21)
  #pragma unroll
  for (int i = 0; i < 4; i++) {
    int flat = tid * 8 + i * 2048;
    // kk/bk: rows of 32 elems (4 chunks of 8); chunk ^= (key>>1)&3
    int key = flat >> 5, qd = (flat >> 3) & 3;
    int sfl = (flat & ~24) | ((qd ^ ((key >> 1) & 3)) << 3);
    async16(&kk_s[flat], k_ws + base + sfl);
    async16(&bk_s[flat], bk_ws + (size_t)h * 8192 + sfl);
    // vT: rows of 256 elems (32 chunks of 8); chunk ^= row&7
    int dd = flat >> 8, cw = (flat >> 3) & 31;
    int vfl = (flat & ~255) | ((cw ^ (dd & 7)) << 3);
    async16(&vT[flat], v_ws + base + vfl);
  }
  __syncthreads();

  // v_mean -> registers. Vectorized b128 reads, swizzle-aware: lane (d, seg) sums
  // 32 positions of row d (phi permutation within a row preserves the sum).
  float* red = (float*)&Pb[0][0];
  {
    int d = tid & 31, seg = tid >> 5;
    float s = 0.f;
    #pragma unroll
    for (int c = 0; c < 4; c++) {
      bf16x8 v = *(const bf16x8*)(&vT[d * 256 + (((seg * 4 + c) ^ (d & 7)) << 3)]);
      #pragma unroll
      for (int j = 0; j < 8; j++) s += bf2f((unsigned short)v[j]);
    }
    red[seg * 32 + d] = s;
  }
  __syncthreads();
  if (tid < 32) {
    float s = 0.f;
    for (int seg = 0; seg < 8; seg++) s += red[seg * 32 + tid];
    red[256 + tid] = val_res_scale[h] * s * (1.0f / 256.0f);
  }
  __syncthreads();
  const float vm_lo = red[256 + l15];
  const float vm_hi = red[256 + 16 + l15];
  __syncthreads();   // all reads of red done before Pb is overwritten

  unsigned short* P = Pb[wv];
  const int xq = (l15 >> 1) & 3;   // kk/bk read swizzle: key=ct*16+l15 -> (key>>1)&3
  const int x7 = l15 & 7;          // vT / P read swizzle mask ((16+l15)&7 == l15&7)

  for (int rt = 0; rt < 4; rt++) {
    // Q frags loaded per-rt (R0 pattern): transient 8 regs each, L2-resident.
    const int m = wv * 64 + rt * 16 + l15;
    bf16x8 aq  = *(const bf16x8*)(q_ws + base + (size_t)m * 32 + quad * 8);
    bf16x8 abq = *(const bf16x8*)(bq_ws + (size_t)h * 8192 + (size_t)m * 32 + quad * 8);

    // QK^T: sacc[ct] = S[q rows rt*16+quad*4+r][key = ct*16+l15]
    f32x4 sacc[16];
    #pragma unroll
    for (int ct = 0; ct < 16; ct++) {
      const int ka = (ct * 16 + l15) * 32 + ((quad ^ xq) << 3);
      bf16x8 b0 = *(const bf16x8*)(&kk_s[ka]);
      bf16x8 b1 = *(const bf16x8*)(&bk_s[ka]);
      f32x4 c = {0.f, 0.f, 0.f, 0.f};
      c = __builtin_amdgcn_mfma_f32_16x16x32_bf16(aq,  b0, c, 0, 0, 0);
      c = __builtin_amdgcn_mfma_f32_16x16x32_bf16(abq, b1, c, 0, 0, 0);
      sacc[ct] = c;
    }
    // per-r softmax (4 independent chains, width-16 static shfl; exp2 domain)
    float rsum[4];
    #pragma unroll
    for (int r = 0; r < 4; r++) {
      float mx = sacc[0][r];
      #pragma unroll
      for (int ct = 1; ct < 16; ct++) mx = fmaxf(mx, sacc[ct][r]);
      #pragma unroll
      for (int off = 1; off < 16; off <<= 1) mx = fmaxf(mx, __shfl_xor(mx, off, 16));
      float s = 0.f;
      #pragma unroll
      for (int ct = 0; ct < 16; ct++) {
        float e = __builtin_amdgcn_exp2f(sacc[ct][r] - mx);   // log2e pre-folded
        sacc[ct][r] = e;
        s += e;
      }
      #pragma unroll
      for (int off = 1; off < 16; off <<= 1) s += __shfl_xor(s, off, 16);
      rsum[r] = s;
    }
    // P write (phi space): key ct*16+l15 -> pos l15*16+ct. Lane's 16 values per
    // row are contiguous: pack via v_cvt_pk_bf16_f32, 2x b128 per row, chunk
    // XOR (row&7) matches PV read. 2-way banks = free (m136).
    #pragma unroll
    for (int r = 0; r < 4; r++) {
      const int row = quad * 4 + r;
      unsigned pk[8];
      #pragma unroll
      for (int i = 0; i < 8; i++)
        asm("v_cvt_pk_bf16_f32 %0, %1, %2"
            : "=v"(pk[i]) : "v"(sacc[2 * i][r]), "v"(sacc[2 * i + 1][r]));
      unsigned short* Prow = P + row * 256;
      *(u32x4*)(Prow + ((((l15 * 2)     ^ (row & 7)) << 3))) = (u32x4){pk[0], pk[1], pk[2], pk[3]};
      *(u32x4*)(Prow + ((((l15 * 2 + 1) ^ (row & 7)) << 3))) = (u32x4){pk[4], pk[5], pk[6], pk[7]};
    }
    __threadfence_block();
    f32x4 o0 = {0.f, 0.f, 0.f, 0.f}, o1 = {0.f, 0.f, 0.f, 0.f};
    #pragma unroll
    for (int s = 0; s < 8; s++) {   // A row=l15, pos chunk (s*4+quad) ^ x7 (P and vT share)
      int cs = (s * 4 + quad) ^ x7;
      bf16x8 ap  = *(const bf16x8*)(&P[l15 * 256 + cs * 8]);
      bf16x8 bv0 = *(const bf16x8*)(&vT[l15 * 256 + cs * 8]);
      bf16x8 bv1 = *(const bf16x8*)(&vT[(16 + l15) * 256 + cs * 8]);
      o0 = __builtin_amdgcn_mfma_f32_16x16x32_bf16(ap, bv0, o0, 0, 0, 0);
      o1 = __builtin_amdgcn_mfma_f32_16x16x32_bf16(ap, bv1, o1, 0, 0, 0);
    }
    const int nrow = wv * 64 + rt * 16 + quad * 4;
    const size_t obase = ((size_t)b * 256 + nrow) * 256 + h * 32;
    #pragma unroll
    for (int r = 0; r < 4; r++) {
      float inv = 1.0f / rsum[r];
      attn_ws[obase + (size_t)r * 256 + l15]      = f2bf(o0[r] * inv + vm_lo);
      attn_ws[obase + (size_t)r * 256 + 16 + l15] = f2bf(o1[r] * inv + vm_hi);
    }
    __threadfence_block();  // P reads drained before next rt overwrites
  }
}

// ---------- K3: out = attn @ proj_w + proj_b (m97 structure, fp32 out) ----------
__global__ __launch_bounds__(256) void proj_kernel(
    const unsigned short* __restrict__ A, const unsigned short* __restrict__ wT,
    const float* __restrict__ wb, float* __restrict__ out) {
  __shared__ unsigned short As[128 * 64];
  __shared__ unsigned short Bs[128 * 64];
  const int tid = threadIdx.x;
  const int n0 = blockIdx.x * 128, r0 = blockIdx.y * 128;
  const int lane = tid & 63, wv = tid >> 6, quad = lane >> 4, l15 = lane & 15;
  const int wm = (wv & 1) * 64, wn = (wv >> 1) * 64;

  f32x4 acc[4][4];
  #pragma unroll
  for (int i = 0; i < 4; i++)
    #pragma unroll
    for (int j = 0; j < 4; j++) acc[i][j] = (f32x4){0.f, 0.f, 0.f, 0.f};

  for (int kk = 0; kk < 256; kk += 64) {
    __syncthreads();
    #pragma unroll
    for (int i = 0; i < 4; i++) {
      int flat = tid * 8 + i * 2048;
      int row = flat >> 6, kc = flat & 63;
      async16(&As[flat], A + (size_t)(r0 + row) * 256 + kk + kc);
      async16(&Bs[flat], wT + (size_t)(n0 + row) * 256 + kk + kc);
    }
    __syncthreads();
    bf16x8 a[4][2], b[4][2];
    #pragma unroll
    for (int rt = 0; rt < 4; rt++) {
      a[rt][0] = *(const bf16x8*)(&As[(wm + rt * 16 + l15) * 64 + quad * 8]);
      a[rt][1] = *(const bf16x8*)(&As[(wm + rt * 16 + l15) * 64 + 32 + quad * 8]);
    }
    #pragma unroll
    for (int ct = 0; ct < 4; ct++) {
      b[ct][0] = *(const bf16x8*)(&Bs[(wn + ct * 16 + l15) * 64 + quad * 8]);
      b[ct][1] = *(const bf16x8*)(&Bs[(wn + ct * 16 + l15) * 64 + 32 + quad * 8]);
    }
    #pragma unroll
    for (int rt = 0; rt < 4; rt++)
      #pragma unroll
      for (int ct = 0; ct < 4; ct++) {
        acc[rt][ct] = __builtin_amdgcn_mfma_f32_16x16x32_bf16(a[rt][0], b[ct][0], acc[rt][ct], 0, 0, 0);
        acc[rt][ct] = __builtin_amdgcn_mfma_f32_16x16x32_bf16(a[rt][1], b[ct][1], acc[rt][ct], 0, 0, 0);
      }
  }
  #pragma unroll
  for (int rt = 0; rt < 4; rt++) {
    const int row = r0 + wm + rt * 16 + quad * 4;
    #pragma unroll
    for (int ct = 0; ct < 4; ct++) {
      const int gc = n0 + wn + ct * 16 + l15;
      const float bc = wb[gc];
      #pragma unroll
      for (int r = 0; r < 4; r++)
        out[(size_t)(row + r) * 256 + gc] = acc[rt][ct][r] + bc;
    }
  }
}

// ---------- launch ----------
extern "C" void kernel_launch(void* const* d_in, const int* in_sizes, int n_in,
                              void* d_out, int out_size, void* d_ws, size_t ws_size,
                              hipStream_t stream) {
  (void)in_sizes; (void)n_in; (void)out_size; (void)ws_size;
  const float* x           = (const float*)d_in[0];
  const float* qkv_w       = (const float*)d_in[1];
  const float* qkv_b       = (const float*)d_in[2];
  const float* proj_w      = (const float*)d_in[3];
  const float* proj_b      = (const float*)d_in[4];
  const float* logit_scale = (const float*)d_in[5];
  const float* val_res_sc  = (const float*)d_in[6];
  const float* mlp1_w      = (const float*)d_in[7];
  const float* mlp1_b      = (const float*)d_in[8];
  const float* mlp2_w      = (const float*)d_in[9];
  const float* bias_scale  = (const float*)d_in[10];
  float* out = (float*)d_out;

  // ws carve (bf16 elems). xb aliases attn_ws: xb consumed by qkv before attn writes it.
  const size_t QKV_ELEMS = (size_t)512 * 8 * 256 * 32;   // 33,554,432 (67 MB)
  unsigned short* q_ws    = (unsigned short*)d_ws;
  unsigned short* k_ws    = q_ws + QKV_ELEMS;
  unsigned short* v_ws    = k_ws + QKV_ELEMS;
  unsigned short* attn_ws = v_ws + QKV_ELEMS;            // also xb
  unsigned short* xb      = attn_ws;
  unsigned short* bq_ws   = attn_ws + QKV_ELEMS;
  unsigned short* bk_ws   = bq_ws + 8 * 256 * 32;
  unsigned short* wT      = bk_ws + 8 * 256 * 32;        // [768][256]
  unsigned short* pwT     = wT + 768 * 256;              // [256][256]

  xcvt_kernel<<<dim3(8192), 256, 0, stream>>>(x, xb);
  wtcvt_kernel<<<dim3(192), 256, 0, stream>>>(qkv_w, wT, 768);
  wtcvt_kernel<<<dim3(64), 256, 0, stream>>>(proj_w, pwT, 256);
  bias_kernel<<<dim3(64), 256, 0, stream>>>(mlp1_w, mlp1_b, mlp2_w, bias_scale, bq_ws, bk_ws);
  qkv_kernel<<<dim3(6, 1024), 256, 0, stream>>>(xb, wT, qkv_b, logit_scale, q_ws, k_ws, v_ws);
  attn_kernel<<<dim3(4096), 256, 0, stream>>>(q_ws, k_ws, v_ws, bq_ws, bk_ws, val_res_sc, attn_ws);
  proj_kernel<<<dim3(2, 1024), 256, 0, stream>>>(attn_ws, pwT, proj_b, out);
}

// Round 8
// 538.861 us; speedup vs baseline: 1.1838x; 1.1838x over previous
//
#include <hip/hip_runtime.h>

// ---------- types / helpers ----------
typedef __attribute__((ext_vector_type(8))) short bf16x8;   // MFMA A/B frag (4 VGPRs)
typedef __attribute__((ext_vector_type(4))) float f32x4;    // MFMA C/D frag
typedef __attribute__((ext_vector_type(4))) unsigned short us4_t;   // 8B bf16 store
typedef __attribute__((ext_vector_type(4))) unsigned int u32x4;    // 16B LDS write

__device__ __forceinline__ unsigned short f2bf(float f) {   // RNE fp32->bf16
  unsigned u = __builtin_bit_cast(unsigned, f);
  u += 0x7fffu + ((u >> 16) & 1u);
  return (unsigned short)(u >> 16);
}
__device__ __forceinline__ float bf2f(unsigned short h) {
  unsigned u = ((unsigned)h) << 16;
  return __builtin_bit_cast(float, u);
}
// async global->LDS DMA, 16B/lane. LDS dst is wave-uniform base + lane*16 (m97/m104).
__device__ __forceinline__ void async16(void* lds, const void* g) {
  __builtin_amdgcn_global_load_lds(
      (const __attribute__((address_space(1))) unsigned int*)g,
      (__attribute__((address_space(3))) unsigned int*)lds, 16, 0, 0);
}

#define LOG2E 1.44269504088896340736f

// ---------- K_pre0: x fp32 -> bf16 (flat) ----------
__global__ __launch_bounds__(256) void xcvt_kernel(const float* __restrict__ x,
                                                   unsigned short* __restrict__ xb) {
  size_t base = ((size_t)blockIdx.x * 256 + threadIdx.x) * 16;
  #pragma unroll
  for (int i = 0; i < 4; i++) {
    float4 v = *(const float4*)(x + base + i * 4);
    us4_t p;
    p[0] = f2bf(v.x); p[1] = f2bf(v.y); p[2] = f2bf(v.z); p[3] = f2bf(v.w);
    *(us4_t*)(xb + base + i * 4) = p;
  }
}

// ---------- K_pre1: w [256][N] fp32 -> wT [N][256] bf16 (transpose+convert, once) ----------
__global__ __launch_bounds__(256) void wtcvt_kernel(const float* __restrict__ w,
                                                    unsigned short* __restrict__ wT, int N) {
  int flat = (blockIdx.x * 256 + threadIdx.x) * 4;   // over 256*N elems
  int k = flat / N, n = flat - k * N;                // 4 consecutive n, same k
  float4 v = *(const float4*)(w + flat);
  wT[(size_t)(n + 0) * 256 + k] = f2bf(v.x);
  wT[(size_t)(n + 1) * 256 + k] = f2bf(v.y);
  wT[(size_t)(n + 2) * 256 + k] = f2bf(v.z);
  wT[(size_t)(n + 3) * 256 + k] = f2bf(v.w);
}

// ---------- K0: rank-factored neural position bias -> bq/bk [H][256][32] bf16 ----------
// 64 blocks x 4 rows; hf in LDS (no scratch), coalesced mlp2_w float4 reads.
// bq carries bias_scale * log2(e) so attention softmax can run in exp2 domain.
__global__ __launch_bounds__(256) void bias_kernel(
    const float* __restrict__ mlp1_w, const float* __restrict__ mlp1_b,
    const float* __restrict__ mlp2_w, const float* __restrict__ bias_scale,
    unsigned short* __restrict__ bq_ws, unsigned short* __restrict__ bk_ws) {
  __shared__ float hf_s[4][128];     // 2 KB
  const int tid = threadIdx.x;
  const int nb = blockIdx.x * 4;     // 64 blocks cover n = 0..255
  const float inv_denom = 0.36067376022224085f;  // 1/log(16)

  // phase 1: 512 hf values per block, 2 per thread (2 erff/thread)
  #pragma unroll
  for (int i = 0; i < 2; i++) {
    int idx = tid + i * 256;                  // 0..511
    int nl = idx >> 7, j = idx & 127;
    int n = nb + nl;
    float c0 = log1pf((float)(n >> 4)) * inv_denom;
    float c1 = log1pf((float)(n & 15)) * inv_denom;
    float t = fmaf(c0, mlp1_w[j], fmaf(c1, mlp1_w[128 + j], mlp1_b[j]));
    hf_s[nl][j] = 0.5f * t * (1.0f + erff(t * 0.70710678118654752f));  // exact gelu
  }
  __syncthreads();

  // phase 2: thread -> (n = nb + tid>>6, cols c0i..c0i+7). hf via LDS broadcast,
  // mlp2_w row j read coalesced (wave covers the 512-float row contiguously).
  const int nl = tid >> 6, n = nb + nl;
  const int c0i = (tid & 63) * 8;
  float acc[8];
  #pragma unroll
  for (int i = 0; i < 8; i++) acc[i] = 0.f;
  for (int j = 0; j < 128; j++) {
    float hv = hf_s[nl][j];
    const float4 w0 = *(const float4*)(mlp2_w + j * 512 + c0i);
    const float4 w1 = *(const float4*)(mlp2_w + j * 512 + c0i + 4);
    acc[0] = fmaf(hv, w0.x, acc[0]); acc[1] = fmaf(hv, w0.y, acc[1]);
    acc[2] = fmaf(hv, w0.z, acc[2]); acc[3] = fmaf(hv, w0.w, acc[3]);
    acc[4] = fmaf(hv, w1.x, acc[4]); acc[5] = fmaf(hv, w1.y, acc[5]);
    acc[6] = fmaf(hv, w1.z, acc[6]); acc[7] = fmaf(hv, w1.w, acc[7]);
  }
  // c = h*64 + qk*32 + r  (8 consecutive r within one (h,qk) block)
  const int h = c0i >> 6, qk = (c0i >> 5) & 1, rb = c0i & 31;
  const float fac = qk ? 1.0f : bias_scale[0] * LOG2E;
  unsigned short* dst = (qk ? bk_ws : bq_ws) + ((size_t)(h * 256 + n)) * 32 + rb;
  us4_t p0, p1;
  #pragma unroll
  for (int i = 0; i < 4; i++) p0[i] = f2bf(fac / (1.f + expf(-acc[i])));
  #pragma unroll
  for (int i = 0; i < 4; i++) p1[i] = f2bf(fac / (1.f + expf(-acc[4 + i])));
  *(us4_t*)dst = p0;
  *(us4_t*)(dst + 4) = p1;
}

// ---------- K1: qkv GEMM (m97 structure). A=xb [M][256], B=wT [768][256], both bf16 k-contig.
// 128x128 tile, BK=64, 256 threads; DMA staging, unpadded stride-64 LDS.
// R8: v-store reverted to CONTIGUOUS us4_t (R7's phi-scattered 2B stores caused
// read-for-ownership + 2.2x write amplification: WRITE_SIZE 442MB vs 205MB ideal).
// phi permutation moved into attn's vT staging (LDS-side, one-time).
__global__ __launch_bounds__(256) void qkv_kernel(
    const unsigned short* __restrict__ xb, const unsigned short* __restrict__ wT,
    const float* __restrict__ wb, const float* __restrict__ logit_scale,
    unsigned short* __restrict__ q_ws, unsigned short* __restrict__ k_ws,
    unsigned short* __restrict__ v_ws) {
  __shared__ unsigned short As[128 * 64];
  __shared__ unsigned short Bs[128 * 64];
  const int tid = threadIdx.x;
  const int n0 = blockIdx.x * 128, r0 = blockIdx.y * 128;
  const int lane = tid & 63, wv = tid >> 6, quad = lane >> 4, l15 = lane & 15;
  const int wm = (wv & 1) * 64, wn = (wv >> 1) * 64;

  f32x4 acc[4][4];
  #pragma unroll
  for (int i = 0; i < 4; i++)
    #pragma unroll
    for (int j = 0; j < 4; j++) acc[i][j] = (f32x4){0.f, 0.f, 0.f, 0.f};

  for (int kk = 0; kk < 256; kk += 64) {
    __syncthreads();
    #pragma unroll
    for (int i = 0; i < 4; i++) {            // flat = tid*8 + i*2048: lane-contig 16B
      int flat = tid * 8 + i * 2048;
      int row = flat >> 6, kc = flat & 63;
      async16(&As[flat], xb + (size_t)(r0 + row) * 256 + kk + kc);
      async16(&Bs[flat], wT + (size_t)(n0 + row) * 256 + kk + kc);
    }
    __syncthreads();                          // barrier drains vmcnt (m97)
    bf16x8 a[4][2], b[4][2];
    #pragma unroll
    for (int rt = 0; rt < 4; rt++) {
      a[rt][0] = *(const bf16x8*)(&As[(wm + rt * 16 + l15) * 64 + quad * 8]);
      a[rt][1] = *(const bf16x8*)(&As[(wm + rt * 16 + l15) * 64 + 32 + quad * 8]);
    }
    #pragma unroll
    for (int ct = 0; ct < 4; ct++) {
      b[ct][0] = *(const bf16x8*)(&Bs[(wn + ct * 16 + l15) * 64 + quad * 8]);
      b[ct][1] = *(const bf16x8*)(&Bs[(wn + ct * 16 + l15) * 64 + 32 + quad * 8]);
    }
    #pragma unroll
    for (int rt = 0; rt < 4; rt++)
      #pragma unroll
      for (int ct = 0; ct < 4; ct++) {
        acc[rt][ct] = __builtin_amdgcn_mfma_f32_16x16x32_bf16(a[rt][0], b[ct][0], acc[rt][ct], 0, 0, 0);
        acc[rt][ct] = __builtin_amdgcn_mfma_f32_16x16x32_bf16(a[rt][1], b[ct][1], acc[rt][ct], 0, 0, 0);
      }
  }
  // epilogue (verified R1): C/D layout col=lane&15, row=quad*4+reg
  #pragma unroll
  for (int rt = 0; rt < 4; rt++) {
    const int rowb = r0 + wm + rt * 16 + quad * 4;
    const int bb = rowb >> 8, n = rowb & 255;
    #pragma unroll
    for (int ct = 0; ct < 4; ct++) {
      const int gc = n0 + wn + ct * 16 + l15;
      const int s = gc >> 8, rem = gc & 255, h = rem >> 5, d = rem & 31;
      const float bc = wb[gc];
      if (s == 2) {  // v transposed [B,H,32,N], contiguous 8B store
        us4_t pk;
        #pragma unroll
        for (int r = 0; r < 4; r++) pk[r] = f2bf(acc[rt][ct][r] + bc);
        *(us4_t*)(v_ws + ((size_t)(bb * 8 + h) * 32 + d) * 256 + n) = pk;
      } else {
        // fold log2e into q so attention softmax runs in exp2 domain
        const float sc = (s == 0) ? logit_scale[h] * LOG2E : 1.0f;
        unsigned short* dst = (s == 0) ? q_ws : k_ws;
        #pragma unroll
        for (int r = 0; r < 4; r++)
          dst[((size_t)(bb * 8 + h) * 256 + (n + r)) * 32 + d] = f2bf((acc[rt][ct][r] + bc) * sc);
      }
    }
  }
}

// ---------- K2: attention per (b,h). LDS = exactly 80 KB -> 2 blocks/CU.
// R8: vT staged via REGISTERS (4x16B global loads, issued before kk/bk DMAs so
// HBM latency hides under them) with phi(K)=(K&15)*16+(K>>4) + chunk-XOR applied
// at ds_write time. Resulting vT contents identical to R7's (verified algebra:
// vT[d][c*8+o] = v_key(phi((c^(d&7))*8+o))), so the R7 P-write (cvt_pk + b128)
// and PV loop carry over unchanged.
__global__ __launch_bounds__(256, 2) void attn_kernel(
    const unsigned short* __restrict__ q_ws, const unsigned short* __restrict__ k_ws,
    const unsigned short* __restrict__ v_ws, const unsigned short* __restrict__ bq_ws,
    const unsigned short* __restrict__ bk_ws, const float* __restrict__ val_res_scale,
    unsigned short* __restrict__ attn_ws) {
  __shared__ unsigned short kk_s[256 * 32];   // [key][d]   swizzled  16 KB
  __shared__ unsigned short bk_s[256 * 32];   // [key][r]   swizzled  16 KB
  __shared__ unsigned short vT[32 * 256];     // [d][pos]   swizzled  16 KB (pos = phi(key))
  __shared__ unsigned short Pb[4][16 * 256];  // per-wave P, XOR-swizzled chunks  32 KB

  const int tid = threadIdx.x;
  const int bh = blockIdx.x, b = bh >> 3, h = bh & 7;
  const size_t base = (size_t)bh * (256 * 32);
  const int lane = tid & 63, wv = tid >> 6, quad = lane >> 4, l15 = lane & 15;

  // v register-stage: issue global loads FIRST (latency hides under the DMAs below)
  bf16x8 vstage[4];
  #pragma unroll
  for (int i = 0; i < 4; i++) {
    int flat = tid * 8 + i * 2048;
    vstage[i] = *(const bf16x8*)(v_ws + base + flat);   // contiguous 16B, coalesced
  }
  // kk/bk staging: linear LDS dest + pre-swizzled global source (rule 21)
  #pragma unroll
  for (int i = 0; i < 4; i++) {
    int flat = tid * 8 + i * 2048;
    int key = flat >> 5, qd = (flat >> 3) & 3;
    int sfl = (flat & ~24) | ((qd ^ ((key >> 1) & 3)) << 3);
    async16(&kk_s[flat], k_ws + base + sfl);
    async16(&bk_s[flat], bk_ws + (size_t)h * 8192 + sfl);
  }
  // vT scatter: phi + chunk-XOR at write time. 8 consecutive keys share K>>4
  // (K0 is 8-aligned, no 16-boundary crossing) -> 8 b16 writes at stride-16 elems.
  #pragma unroll
  for (int i = 0; i < 4; i++) {
    int flat = tid * 8 + i * 2048;
    int d = flat >> 8, K0 = flat & 255;
    int k15 = K0 & 15, c0 = K0 >> 4, hb = c0 >> 3, lo = c0 & 7;
    int x = d & 7;
    #pragma unroll
    for (int j = 0; j < 8; j++) {
      int chunk = 2 * (k15 + j) + hb;        // pos = (k15+j)*16 + c0; chunk = pos>>3
      vT[d * 256 + ((chunk ^ x) << 3) + lo] = (unsigned short)vstage[i][j];
    }
  }
  __syncthreads();

  // v_mean -> registers. Vectorized b128 reads, swizzle-aware: lane (d, seg) sums
  // 32 positions of row d (phi permutation within a row preserves the sum).
  float* red = (float*)&Pb[0][0];
  {
    int d = tid & 31, seg = tid >> 5;
    float s = 0.f;
    #pragma unroll
    for (int c = 0; c < 4; c++) {
      bf16x8 v = *(const bf16x8*)(&vT[d * 256 + (((seg * 4 + c) ^ (d & 7)) << 3)]);
      #pragma unroll
      for (int j = 0; j < 8; j++) s += bf2f((unsigned short)v[j]);
    }
    red[seg * 32 + d] = s;
  }
  __syncthreads();
  if (tid < 32) {
    float s = 0.f;
    for (int seg = 0; seg < 8; seg++) s += red[seg * 32 + tid];
    red[256 + tid] = val_res_scale[h] * s * (1.0f / 256.0f);
  }
  __syncthreads();
  const float vm_lo = red[256 + l15];
  const float vm_hi = red[256 + 16 + l15];
  __syncthreads();   // all reads of red done before Pb is overwritten

  unsigned short* P = Pb[wv];
  const int xq = (l15 >> 1) & 3;   // kk/bk read swizzle: key=ct*16+l15 -> (key>>1)&3
  const int x7 = l15 & 7;          // vT / P read swizzle mask ((16+l15)&7 == l15&7)

  for (int rt = 0; rt < 4; rt++) {
    // Q frags loaded per-rt (R0 pattern): transient 8 regs each, L2-resident.
    const int m = wv * 64 + rt * 16 + l15;
    bf16x8 aq  = *(const bf16x8*)(q_ws + base + (size_t)m * 32 + quad * 8);
    bf16x8 abq = *(const bf16x8*)(bq_ws + (size_t)h * 8192 + (size_t)m * 32 + quad * 8);

    // QK^T: sacc[ct] = S[q rows rt*16+quad*4+r][key = ct*16+l15]
    f32x4 sacc[16];
    #pragma unroll
    for (int ct = 0; ct < 16; ct++) {
      const int ka = (ct * 16 + l15) * 32 + ((quad ^ xq) << 3);
      bf16x8 b0 = *(const bf16x8*)(&kk_s[ka]);
      bf16x8 b1 = *(const bf16x8*)(&bk_s[ka]);
      f32x4 c = {0.f, 0.f, 0.f, 0.f};
      c = __builtin_amdgcn_mfma_f32_16x16x32_bf16(aq,  b0, c, 0, 0, 0);
      c = __builtin_amdgcn_mfma_f32_16x16x32_bf16(abq, b1, c, 0, 0, 0);
      sacc[ct] = c;
    }
    // per-r softmax (4 independent chains, width-16 static shfl; exp2 domain)
    float rsum[4];
    #pragma unroll
    for (int r = 0; r < 4; r++) {
      float mx = sacc[0][r];
      #pragma unroll
      for (int ct = 1; ct < 16; ct++) mx = fmaxf(mx, sacc[ct][r]);
      #pragma unroll
      for (int off = 1; off < 16; off <<= 1) mx = fmaxf(mx, __shfl_xor(mx, off, 16));
      float s = 0.f;
      #pragma unroll
      for (int ct = 0; ct < 16; ct++) {
        float e = __builtin_amdgcn_exp2f(sacc[ct][r] - mx);   // log2e pre-folded
        sacc[ct][r] = e;
        s += e;
      }
      #pragma unroll
      for (int off = 1; off < 16; off <<= 1) s += __shfl_xor(s, off, 16);
      rsum[r] = s;
    }
    // P write (phi space): key ct*16+l15 -> pos l15*16+ct. Lane's 16 values per
    // row are contiguous: pack via v_cvt_pk_bf16_f32, 2x b128 per row, chunk
    // XOR (row&7) matches PV read. 2-way banks = free (m136).
    #pragma unroll
    for (int r = 0; r < 4; r++) {
      const int row = quad * 4 + r;
      unsigned pk[8];
      #pragma unroll
      for (int i = 0; i < 8; i++)
        asm("v_cvt_pk_bf16_f32 %0, %1, %2"
            : "=v"(pk[i]) : "v"(sacc[2 * i][r]), "v"(sacc[2 * i + 1][r]));
      unsigned short* Prow = P + row * 256;
      *(u32x4*)(Prow + ((((l15 * 2)     ^ (row & 7)) << 3))) = (u32x4){pk[0], pk[1], pk[2], pk[3]};
      *(u32x4*)(Prow + ((((l15 * 2 + 1) ^ (row & 7)) << 3))) = (u32x4){pk[4], pk[5], pk[6], pk[7]};
    }
    __threadfence_block();
    f32x4 o0 = {0.f, 0.f, 0.f, 0.f}, o1 = {0.f, 0.f, 0.f, 0.f};
    #pragma unroll
    for (int s = 0; s < 8; s++) {   // A row=l15, pos chunk (s*4+quad) ^ x7 (P and vT share)
      int cs = (s * 4 + quad) ^ x7;
      bf16x8 ap  = *(const bf16x8*)(&P[l15 * 256 + cs * 8]);
      bf16x8 bv0 = *(const bf16x8*)(&vT[l15 * 256 + cs * 8]);
      bf16x8 bv1 = *(const bf16x8*)(&vT[(16 + l15) * 256 + cs * 8]);
      o0 = __builtin_amdgcn_mfma_f32_16x16x32_bf16(ap, bv0, o0, 0, 0, 0);
      o1 = __builtin_amdgcn_mfma_f32_16x16x32_bf16(ap, bv1, o1, 0, 0, 0);
    }
    const int nrow = wv * 64 + rt * 16 + quad * 4;
    const size_t obase = ((size_t)b * 256 + nrow) * 256 + h * 32;
    #pragma unroll
    for (int r = 0; r < 4; r++) {
      float inv = 1.0f / rsum[r];
      attn_ws[obase + (size_t)r * 256 + l15]      = f2bf(o0[r] * inv + vm_lo);
      attn_ws[obase + (size_t)r * 256 + 16 + l15] = f2bf(o1[r] * inv + vm_hi);
    }
    __threadfence_block();  // P reads drained before next rt overwrites
  }
}

// ---------- K3: out = attn @ proj_w + proj_b (m97 structure, fp32 out) ----------
__global__ __launch_bounds__(256) void proj_kernel(
    const unsigned short* __restrict__ A, const unsigned short* __restrict__ wT,
    const float* __restrict__ wb, float* __restrict__ out) {
  __shared__ unsigned short As[128 * 64];
  __shared__ unsigned short Bs[128 * 64];
  const int tid = threadIdx.x;
  const int n0 = blockIdx.x * 128, r0 = blockIdx.y * 128;
  const int lane = tid & 63, wv = tid >> 6, quad = lane >> 4, l15 = lane & 15;
  const int wm = (wv & 1) * 64, wn = (wv >> 1) * 64;

  f32x4 acc[4][4];
  #pragma unroll
  for (int i = 0; i < 4; i++)
    #pragma unroll
    for (int j = 0; j < 4; j++) acc[i][j] = (f32x4){0.f, 0.f, 0.f, 0.f};

  for (int kk = 0; kk < 256; kk += 64) {
    __syncthreads();
    #pragma unroll
    for (int i = 0; i < 4; i++) {
      int flat = tid * 8 + i * 2048;
      int row = flat >> 6, kc = flat & 63;
      async16(&As[flat], A + (size_t)(r0 + row) * 256 + kk + kc);
      async16(&Bs[flat], wT + (size_t)(n0 + row) * 256 + kk + kc);
    }
    __syncthreads();
    bf16x8 a[4][2], b[4][2];
    #pragma unroll
    for (int rt = 0; rt < 4; rt++) {
      a[rt][0] = *(const bf16x8*)(&As[(wm + rt * 16 + l15) * 64 + quad * 8]);
      a[rt][1] = *(const bf16x8*)(&As[(wm + rt * 16 + l15) * 64 + 32 + quad * 8]);
    }
    #pragma unroll
    for (int ct = 0; ct < 4; ct++) {
      b[ct][0] = *(const bf16x8*)(&Bs[(wn + ct * 16 + l15) * 64 + quad * 8]);
      b[ct][1] = *(const bf16x8*)(&Bs[(wn + ct * 16 + l15) * 64 + 32 + quad * 8]);
    }
    #pragma unroll
    for (int rt = 0; rt < 4; rt++)
      #pragma unroll
      for (int ct = 0; ct < 4; ct++) {
        acc[rt][ct] = __builtin_amdgcn_mfma_f32_16x16x32_bf16(a[rt][0], b[ct][0], acc[rt][ct], 0, 0, 0);
        acc[rt][ct] = __builtin_amdgcn_mfma_f32_16x16x32_bf16(a[rt][1], b[ct][1], acc[rt][ct], 0, 0, 0);
      }
  }
  #pragma unroll
  for (int rt = 0; rt < 4; rt++) {
    const int row = r0 + wm + rt * 16 + quad * 4;
    #pragma unroll
    for (int ct = 0; ct < 4; ct++) {
      const int gc = n0 + wn + ct * 16 + l15;
      const float bc = wb[gc];
      #pragma unroll
      for (int r = 0; r < 4; r++)
        out[(size_t)(row + r) * 256 + gc] = acc[rt][ct][r] + bc;
    }
  }
}

// ---------- launch ----------
extern "C" void kernel_launch(void* const* d_in, const int* in_sizes, int n_in,
                              void* d_out, int out_size, void* d_ws, size_t ws_size,
                              hipStream_t stream) {
  (void)in_sizes; (void)n_in; (void)out_size; (void)ws_size;
  const float* x           = (const float*)d_in[0];
  const float* qkv_w       = (const float*)d_in[1];
  const float* qkv_b       = (const float*)d_in[2];
  const float* proj_w      = (const float*)d_in[3];
  const float* proj_b      = (const float*)d_in[4];
  const float* logit_scale = (const float*)d_in[5];
  const float* val_res_sc  = (const float*)d_in[6];
  const float* mlp1_w      = (const float*)d_in[7];
  const float* mlp1_b      = (const float*)d_in[8];
  const float* mlp2_w      = (const float*)d_in[9];
  const float* bias_scale  = (const float*)d_in[10];
  float* out = (float*)d_out;

  // ws carve (bf16 elems). xb aliases attn_ws: xb consumed by qkv before attn writes it.
  const size_t QKV_ELEMS = (size_t)512 * 8 * 256 * 32;   // 33,554,432 (67 MB)
  unsigned short* q_ws    = (unsigned short*)d_ws;
  unsigned short* k_ws    = q_ws + QKV_ELEMS;
  unsigned short* v_ws    = k_ws + QKV_ELEMS;
  unsigned short* attn_ws = v_ws + QKV_ELEMS;            // also xb
  unsigned short* xb      = attn_ws;
  unsigned short* bq_ws   = attn_ws + QKV_ELEMS;
  unsigned short* bk_ws   = bq_ws + 8 * 256 * 32;
  unsigned short* wT      = bk_ws + 8 * 256 * 32;        // [768][256]
  unsigned short* pwT     = wT + 768 * 256;              // [256][256]

  xcvt_kernel<<<dim3(8192), 256, 0, stream>>>(x, xb);
  wtcvt_kernel<<<dim3(192), 256, 0, stream>>>(qkv_w, wT, 768);
  wtcvt_kernel<<<dim3(64), 256, 0, stream>>>(proj_w, pwT, 256);
  bias_kernel<<<dim3(64), 256, 0, stream>>>(mlp1_w, mlp1_b, mlp2_w, bias_scale, bq_ws, bk_ws);
  qkv_kernel<<<dim3(6, 1024), 256, 0, stream>>>(xb, wT, qkv_b, logit_scale, q_ws, k_ws, v_ws);
  attn_kernel<<<dim3(4096), 256, 0, stream>>>(q_ws, k_ws, v_ws, bq_ws, bk_ws, val_res_sc, attn_ws);
  proj_kernel<<<dim3(2, 1024), 256, 0, stream>>>(attn_ws, pwT, proj_b, out);
}